// Round 14
// baseline (48.646 us; speedup 1.0000x reference)
//
#include <hip/hip_runtime.h>

typedef _Float16 f16;
typedef f16 half8 __attribute__((ext_vector_type(8)));
typedef float f32x16 __attribute__((ext_vector_type(16)));

#define BB 8
#define NN 8192
#define SETPTS (BB * NN)   // 65536 points per set
#define NPTS (2 * SETPTS)  // 131072 total points
#define TQ NPTS            // total queries

__device__ __forceinline__ void gload_lds16(const void* g, void* l) {
  __builtin_amdgcn_global_load_lds(
      (const __attribute__((address_space(1))) void*)g,
      (__attribute__((address_space(3))) void*)l, 16, 0, 0);
}

// ---------------- prep: build fp16-split MFMA operands ----------------
// Q-rep (point as query):  per coord (h,l,h,l); tail (1,1,0,0)
// R-rep (point as ref):    per coord (H,H,L,L) of -2y; tail (yy_h,yy_l,0,0)
// products per coord: hH + lH + hL + lL = (h+l)(H+L)  [exact in fp32 accum]
__global__ __launch_bounds__(256) void chamfer_prep(
    const float* __restrict__ preds, const float* __restrict__ gts,
    float* __restrict__ yy, half8* __restrict__ Aq, half8* __restrict__ Bq) {
  int idx = blockIdx.x * 256 + threadIdx.x;  // 0..NPTS-1
  int s = idx >> 16;                         // set: 0=preds, 1=gts
  int off = idx & (SETPTS - 1);
  const float* src = s ? gts : preds;
  float x0 = src[off * 3 + 0], x1 = src[off * 3 + 1], x2 = src[off * 3 + 2];

  f16 h0 = (f16)x0; f16 l0 = (f16)(x0 - (float)h0);
  f16 h1 = (f16)x1; f16 l1 = (f16)(x1 - (float)h1);
  f16 h2 = (f16)x2; f16 l2 = (f16)(x2 - (float)h2);

  float Y0 = -2.f * x0, Y1 = -2.f * x1, Y2 = -2.f * x2;
  f16 H0 = (f16)Y0; f16 L0 = (f16)(Y0 - (float)H0);
  f16 H1 = (f16)Y1; f16 L1 = (f16)(Y1 - (float)H1);
  f16 H2 = (f16)Y2; f16 L2 = (f16)(Y2 - (float)H2);

  float yv = x0 * x0 + x1 * x1 + x2 * x2;
  f16 yh = (f16)yv; f16 yl = (f16)(yv - (float)yh);

  f16 one = (f16)1.f, zz = (f16)0.f;
  half8 A0 = {h0, l0, h0, l0, h1, l1, h1, l1};
  half8 A1 = {h2, l2, h2, l2, one, one, zz, zz};
  half8 B0 = {H0, H0, L0, L0, H1, H1, L1, L1};
  half8 B1 = {H2, H2, L2, L2, yh, yl, zz, zz};

  Aq[idx * 2 + 0] = A0; Aq[idx * 2 + 1] = A1;
  Bq[idx * 2 + 0] = B0; Bq[idx * 2 + 1] = B1;
  yy[idx] = yv;
}

// ---------------- main: MFMA distance tiles, SWAPPED operands ------------
// r12 inner step byte-identical; ONE structural variable: R=16 short blocks.
// Each block: stage its 16KB ref-slice ONCE -> one barrier -> NSTEP straight
// steps -> tiny epilogue. No inner barriers / double-buffer. ~8-10 short
// blocks/CU at DIFFERENT phases: one block's stage overlaps another's
// MFMA+min (phase diversity does the latency hiding that barrier-locked
// chunks prevented in r9-r13).
// D[ref][query]: per lane 16 output regs = 16 refs of ONE query ->
// per-step v_min3 tree into a SCALAR running min; epilogue 2 shfl + stores.
template <int R>
__global__ __launch_bounds__(256, 4) void chamfer_mfma(
    const half8* __restrict__ Aq, const half8* __restrict__ Bq,
    float* __restrict__ partial) {
  constexpr int NSTEP = NN / R / 32;  // tiles per block (R=16 -> 16)
  __shared__ __align__(16) char lds[NSTEP * 1024];

  // ---- XCD swizzle: xcd = bi & 7 (round-robin dispatch, m157) ----
  // 16 panels (dir,b); 2 panels per XCD; 32*R blocks per panel.
  int bi = blockIdx.x;
  int xcd = bi & 7;
  int idx = bi >> 3;                 // 0 .. 2*(32*R)-1
  int panel = xcd * 2 + (idx & 1);   // 0..15
  int dir = panel >> 3;
  int b = panel & 7;
  int sub = idx >> 1;                // 0 .. 32*R-1
  int qb = sub & 31;
  int r = sub >> 5;                  // 0..R-1

  int tid = threadIdx.x;
  int w = tid >> 6;
  int l = tid & 63;
  int l31 = l & 31;
  int lh = l >> 5;

  // queries as B-operand: q0 = cols 0..31 (wave queries +0..31), q1 = +32..63
  const half8* Qp =
      Aq + ((size_t)(dir * BB + b) * NN + qb * 256 + w * 64) * 2;
  half8 q0 = Qp[l31 * 2 + lh];
  half8 q1 = Qp[(32 + l31) * 2 + lh];

  // B panel slice for this block, as bytes. Tile = 1024 B = 32 refs.
  const char* gpanel = (const char*)(Bq + ((size_t)((1 - dir) * BB + b) * NN +
                                           r * (NN / R)) * 2);
  // pre-permuted per-lane source offset: lane l stages the element it reads
  int perm = ((l & 31) * 2 + (l >> 5)) * 16;

  // stage the whole slice once: wave w stages tiles [w*NSTEP/4, +NSTEP/4)
  {
    constexpr int TPW = NSTEP / 4;
    const char* csrc = gpanel + (size_t)(w * TPW) * 1024 + perm;
    char* cdst = &lds[w * TPW * 1024];
#pragma unroll
    for (int i = 0; i < TPW; ++i)
      gload_lds16(csrc + i * 1024, cdst + i * 1024);
  }

  f32x16 zero;
#pragma unroll
  for (int i = 0; i < 16; ++i) zero[i] = 0.f;
  float run0 = 3.4e38f, run1 = 3.4e38f;

  __syncthreads();  // drains vmcnt then barrier: slice resident

  const half8* lb = (const half8*)&lds[0];
#pragma unroll 4
  for (int st = 0; st < NSTEP; ++st) {
    half8 bt = lb[st * 64 + l];  // ds_read_b128, conflict-free; A-operand
    f32x16 oa = __builtin_amdgcn_mfma_f32_32x32x16_f16(bt, q0, zero, 0, 0, 0);
    f32x16 ob = __builtin_amdgcn_mfma_f32_32x32x16_f16(bt, q1, zero, 0, 0, 0);
    {  // v_min3 tree: 16 refs -> scalar, fold into run0
      float t0 = fminf(fminf(oa[0], oa[1]), oa[2]);
      float t1 = fminf(fminf(oa[3], oa[4]), oa[5]);
      float t2 = fminf(fminf(oa[6], oa[7]), oa[8]);
      float t3 = fminf(fminf(oa[9], oa[10]), oa[11]);
      float t4 = fminf(fminf(oa[12], oa[13]), oa[14]);
      float u0 = fminf(fminf(t0, t1), t2);
      float u1 = fminf(fminf(t3, t4), oa[15]);
      run0 = fminf(fminf(run0, u0), u1);
    }
    {
      float t0 = fminf(fminf(ob[0], ob[1]), ob[2]);
      float t1 = fminf(fminf(ob[3], ob[4]), ob[5]);
      float t2 = fminf(fminf(ob[6], ob[7]), ob[8]);
      float t3 = fminf(fminf(ob[9], ob[10]), ob[11]);
      float t4 = fminf(fminf(ob[12], ob[13]), ob[14]);
      float u0 = fminf(fminf(t0, t1), t2);
      float u1 = fminf(fminf(t3, t4), ob[15]);
      run1 = fminf(fminf(run1, u0), u1);
    }
  }

  // cross-half combine (lane l <-> l+32 hold complementary ref rows)
  float v0 = fminf(run0, __shfl_xor(run0, 32));
  float v1 = fminf(run1, __shfl_xor(run1, 32));

  size_t qflat = (size_t)(dir * BB + b) * NN + qb * 256 + w * 64;
  float* pr = partial + (size_t)r * TQ + qflat;
  if (lh == 0) {
    pr[l31] = v0;        // queries +0..31, coalesced
    pr[32 + l31] = v1;   // queries +32..63
  }
}

// ---------------- combine: min over R slices + query norm, block sum -----
template <int R>
__global__ __launch_bounds__(256) void chamfer_combine(
    const float* __restrict__ partial, const float* __restrict__ yy,
    float* __restrict__ bsums) {
  int q = blockIdx.x * 256 + threadIdx.x;
  float m = partial[q];
#pragma unroll
  for (int rr = 1; rr < R; ++rr) m = fminf(m, partial[(size_t)rr * TQ + q]);
  m += yy[q];
  __shared__ float s[256];
  s[threadIdx.x] = m;
  __syncthreads();
  for (int o = 128; o > 0; o >>= 1) {
    if (threadIdx.x < o) s[threadIdx.x] += s[threadIdx.x + o];
    __syncthreads();
  }
  if (threadIdx.x == 0) bsums[blockIdx.x] = s[0];
}

__global__ __launch_bounds__(256) void chamfer_final(
    const float* __restrict__ bsums, float* __restrict__ out, int n) {
  float v = 0.f;
  for (int i = threadIdx.x; i < n; i += 256) v += bsums[i];
  __shared__ float s[256];
  s[threadIdx.x] = v;
  __syncthreads();
  for (int o = 128; o > 0; o >>= 1) {
    if (threadIdx.x < o) s[threadIdx.x] += s[threadIdx.x + o];
    __syncthreads();
  }
  if (threadIdx.x == 0) out[0] = s[0];
}

extern "C" void kernel_launch(void* const* d_in, const int* in_sizes, int n_in,
                              void* d_out, int out_size, void* d_ws,
                              size_t ws_size, hipStream_t stream) {
  const float* preds = (const float*)d_in[0];
  const float* gts = (const float*)d_in[1];
  float* out = (float*)d_out;

  // ws layout (floats): partial[R*TQ] | bsums[1024] | yy[NPTS] | Aq | Bq
  size_t fixed = (size_t)1024 * 4 + (size_t)NPTS * 4 + (size_t)NPTS * 64;
  int R = (ws_size >= (size_t)16 * TQ * 4 + fixed) ? 16 : 8;

  float* partial = (float*)d_ws;
  float* bsums = partial + (size_t)R * TQ;
  float* yy = bsums + 1024;
  half8* Aq = (half8*)(yy + NPTS);
  half8* Bq = Aq + (size_t)NPTS * 2;

  chamfer_prep<<<NPTS / 256, 256, 0, stream>>>(preds, gts, yy, Aq, Bq);
  if (R == 16) {
    chamfer_mfma<16><<<2 * BB * 32 * 16, 256, 0, stream>>>(Aq, Bq, partial);
    chamfer_combine<16><<<TQ / 256, 256, 0, stream>>>(partial, yy, bsums);
  } else {
    chamfer_mfma<8><<<2 * BB * 32 * 8, 256, 0, stream>>>(Aq, Bq, partial);
    chamfer_combine<8><<<TQ / 256, 256, 0, stream>>>(partial, yy, bsums);
  }
  chamfer_final<<<1, 256, 0, stream>>>(bsums, out, TQ / 256);
}

// Round 15
// 45.757 us; speedup vs baseline: 1.0632x; 1.0632x over previous
//
#include <hip/hip_runtime.h>

typedef _Float16 f16;
typedef f16 half8 __attribute__((ext_vector_type(8)));
typedef float f32x16 __attribute__((ext_vector_type(16)));

#define BB 8
#define NN 8192
#define SETPTS (BB * NN)   // 65536 points per set
#define NPTS (2 * SETPTS)  // 131072 total points
#define TQ NPTS            // total queries

__device__ __forceinline__ void gload_lds16(const void* g, void* l) {
  __builtin_amdgcn_global_load_lds(
      (const __attribute__((address_space(1))) void*)g,
      (__attribute__((address_space(3))) void*)l, 16, 0, 0);
}

// ---------------- prep: build fp16-split MFMA operands ----------------
// Q-rep (point as query):  per coord (h,l,h,l); tail (1,1,0,0)
// R-rep (point as ref):    per coord (H,H,L,L) of -2y; tail (yy_h,yy_l,0,0)
// products per coord: hH + lH + hL + lL = (h+l)(H+L)  [exact in fp32 accum]
__global__ __launch_bounds__(256) void chamfer_prep(
    const float* __restrict__ preds, const float* __restrict__ gts,
    float* __restrict__ yy, half8* __restrict__ Aq, half8* __restrict__ Bq) {
  int idx = blockIdx.x * 256 + threadIdx.x;  // 0..NPTS-1
  int s = idx >> 16;                         // set: 0=preds, 1=gts
  int off = idx & (SETPTS - 1);
  const float* src = s ? gts : preds;
  float x0 = src[off * 3 + 0], x1 = src[off * 3 + 1], x2 = src[off * 3 + 2];

  f16 h0 = (f16)x0; f16 l0 = (f16)(x0 - (float)h0);
  f16 h1 = (f16)x1; f16 l1 = (f16)(x1 - (float)h1);
  f16 h2 = (f16)x2; f16 l2 = (f16)(x2 - (float)h2);

  float Y0 = -2.f * x0, Y1 = -2.f * x1, Y2 = -2.f * x2;
  f16 H0 = (f16)Y0; f16 L0 = (f16)(Y0 - (float)H0);
  f16 H1 = (f16)Y1; f16 L1 = (f16)(Y1 - (float)H1);
  f16 H2 = (f16)Y2; f16 L2 = (f16)(Y2 - (float)H2);

  float yv = x0 * x0 + x1 * x1 + x2 * x2;
  f16 yh = (f16)yv; f16 yl = (f16)(yv - (float)yh);

  f16 one = (f16)1.f, zz = (f16)0.f;
  half8 A0 = {h0, l0, h0, l0, h1, l1, h1, l1};
  half8 A1 = {h2, l2, h2, l2, one, one, zz, zz};
  half8 B0 = {H0, H0, L0, L0, H1, H1, L1, L1};
  half8 B1 = {H2, H2, L2, L2, yh, yl, zz, zz};

  Aq[idx * 2 + 0] = A0; Aq[idx * 2 + 1] = A1;
  Bq[idx * 2 + 0] = B0; Bq[idx * 2 + 1] = B1;
  yy[idx] = yv;
}

// ---------------- main: MFMA distance tiles, 4 query-frags/wave ----------
// r12 base (CH=16 dbuf staging, XCD swizzle, scalar-run min trees, swapped
// operands D[ref][query]); ONE variable: 128 queries/wave (q0..q3) -> each
// ds_read_b128 feeds 4 MFMA. Wave-steps halve (524k -> 262k): LDS-pipe
// demand and per-pair stall exposure halve. Running state stays 4 SCALARS
// (r11's f32x16-state AGPR trap avoided); transients sequenced 2+2.
template <int R>
__global__ __launch_bounds__(256, 4) void chamfer_mfma(
    const half8* __restrict__ Aq, const half8* __restrict__ Bq,
    float* __restrict__ partial) {
  constexpr int NSTEP = NN / R / 32;  // b-tiles per block (R=4 -> 64)
  constexpr int CH = 16;              // tiles per chunk (16 KB)
  constexpr int NCH = NSTEP / CH;     // chunks (R=4 -> 4)
  __shared__ __align__(16) char lds[2][CH * 1024];

  // ---- XCD swizzle: xcd = bi & 7 (round-robin dispatch) ----
  // 16 panels (dir,b); 2 panels per XCD; 16(qb) x R blocks per panel.
  int bi = blockIdx.x;
  int xcd = bi & 7;
  int idx = bi >> 3;                 // 0 .. 2*16*R-1
  int panel = xcd * 2 + (idx & 1);   // 0..15
  int dir = panel >> 3;
  int b = panel & 7;
  int sub = idx >> 1;                // 0 .. 16*R-1
  int qb = sub & 15;
  int r = sub >> 4;                  // 0..R-1

  int tid = threadIdx.x;
  int w = tid >> 6;
  int l = tid & 63;
  int l31 = l & 31;
  int lh = l >> 5;

  // queries as B-operand: wave w owns queries [qb*2048 + w*128, +128)
  const half8* Qp =
      Aq + ((size_t)(dir * BB + b) * NN + qb * 512 + w * 128) * 2;
  half8 q0 = Qp[(0 * 32 + l31) * 2 + lh];
  half8 q1 = Qp[(1 * 32 + l31) * 2 + lh];
  half8 q2 = Qp[(2 * 32 + l31) * 2 + lh];
  half8 q3 = Qp[(3 * 32 + l31) * 2 + lh];

  // B panel slice for this block, as bytes. Tile = 1024 B = 32 refs.
  const char* gpanel = (const char*)(Bq + ((size_t)((1 - dir) * BB + b) * NN +
                                           r * (NN / R)) * 2);
  // pre-permuted per-lane source offset: lane l stages the element it reads
  int perm = ((l & 31) * 2 + (l >> 5)) * 16;

  // wave w stages tiles [w*4, w*4+4) of each chunk
  auto stage = [&](int buf, int c) {
    const char* csrc = gpanel + (size_t)(c * CH + w * 4) * 1024 + perm;
    char* cdst = &lds[buf][w * 4 * 1024];
#pragma unroll
    for (int i = 0; i < 4; ++i)
      gload_lds16(csrc + i * 1024, cdst + i * 1024);
  };

  f32x16 zero;
#pragma unroll
  for (int i = 0; i < 16; ++i) zero[i] = 0.f;
  float run0 = 3.4e38f, run1 = 3.4e38f, run2 = 3.4e38f, run3 = 3.4e38f;

#define MINTREE(o, run)                                   \
  {                                                       \
    float t0 = fminf(fminf(o[0], o[1]), o[2]);            \
    float t1 = fminf(fminf(o[3], o[4]), o[5]);            \
    float t2 = fminf(fminf(o[6], o[7]), o[8]);            \
    float t3 = fminf(fminf(o[9], o[10]), o[11]);          \
    float t4 = fminf(fminf(o[12], o[13]), o[14]);         \
    float u0 = fminf(fminf(t0, t1), t2);                  \
    float u1 = fminf(fminf(t3, t4), o[15]);               \
    run = fminf(fminf(run, u0), u1);                      \
  }

  stage(0, 0);
  __syncthreads();  // drains vmcnt then barrier: chunk 0 resident

#pragma unroll 1
  for (int ch = 0; ch < NCH; ++ch) {
    int par = ch & 1;
    if (ch + 1 < NCH) stage(par ^ 1, ch + 1);  // async prefetch next chunk
    const half8* lb = (const half8*)&lds[par][0];
#pragma unroll 2
    for (int st = 0; st < CH; ++st) {
      half8 bt = lb[st * 64 + l];  // ds_read_b128, conflict-free; A-operand
      f32x16 oa = __builtin_amdgcn_mfma_f32_32x32x16_f16(bt, q0, zero, 0, 0, 0);
      f32x16 ob = __builtin_amdgcn_mfma_f32_32x32x16_f16(bt, q1, zero, 0, 0, 0);
      MINTREE(oa, run0)
      MINTREE(ob, run1)
      f32x16 oc = __builtin_amdgcn_mfma_f32_32x32x16_f16(bt, q2, zero, 0, 0, 0);
      f32x16 od = __builtin_amdgcn_mfma_f32_32x32x16_f16(bt, q3, zero, 0, 0, 0);
      MINTREE(oc, run2)
      MINTREE(od, run3)
    }
    __syncthreads();  // all reads of lds[par] done; prefetch drained
  }
#undef MINTREE

  // cross-half combine (lane l <-> l+32 hold complementary ref rows)
  float v0 = fminf(run0, __shfl_xor(run0, 32));
  float v1 = fminf(run1, __shfl_xor(run1, 32));
  float v2 = fminf(run2, __shfl_xor(run2, 32));
  float v3 = fminf(run3, __shfl_xor(run3, 32));

  size_t qflat = (size_t)(dir * BB + b) * NN + qb * 512 + w * 128;
  float* pr = partial + (size_t)r * TQ + qflat;
  if (lh == 0) {
    pr[l31] = v0;         // queries +0..31, coalesced
    pr[32 + l31] = v1;    // +32..63
    pr[64 + l31] = v2;    // +64..95
    pr[96 + l31] = v3;    // +96..127
  }
}

// ---------------- combine: min over R slices + query norm, block sum -----
template <int R>
__global__ __launch_bounds__(256) void chamfer_combine(
    const float* __restrict__ partial, const float* __restrict__ yy,
    float* __restrict__ bsums) {
  int q = blockIdx.x * 256 + threadIdx.x;
  float m = partial[q];
#pragma unroll
  for (int rr = 1; rr < R; ++rr) m = fminf(m, partial[(size_t)rr * TQ + q]);
  m += yy[q];
  __shared__ float s[256];
  s[threadIdx.x] = m;
  __syncthreads();
  for (int o = 128; o > 0; o >>= 1) {
    if (threadIdx.x < o) s[threadIdx.x] += s[threadIdx.x + o];
    __syncthreads();
  }
  if (threadIdx.x == 0) bsums[blockIdx.x] = s[0];
}

__global__ __launch_bounds__(256) void chamfer_final(
    const float* __restrict__ bsums, float* __restrict__ out, int n) {
  float v = 0.f;
  for (int i = threadIdx.x; i < n; i += 256) v += bsums[i];
  __shared__ float s[256];
  s[threadIdx.x] = v;
  __syncthreads();
  for (int o = 128; o > 0; o >>= 1) {
    if (threadIdx.x < o) s[threadIdx.x] += s[threadIdx.x + o];
    __syncthreads();
  }
  if (threadIdx.x == 0) out[0] = s[0];
}

extern "C" void kernel_launch(void* const* d_in, const int* in_sizes, int n_in,
                              void* d_out, int out_size, void* d_ws,
                              size_t ws_size, hipStream_t stream) {
  const float* preds = (const float*)d_in[0];
  const float* gts = (const float*)d_in[1];
  float* out = (float*)d_out;

  // ws layout (floats): partial[R*TQ] | bsums[1024] | yy[NPTS] | Aq | Bq
  const int R = 4;
  float* partial = (float*)d_ws;
  float* bsums = partial + (size_t)R * TQ;
  float* yy = bsums + 1024;
  half8* Aq = (half8*)(yy + NPTS);
  half8* Bq = Aq + (size_t)NPTS * 2;

  chamfer_prep<<<NPTS / 256, 256, 0, stream>>>(preds, gts, yy, Aq, Bq);
  chamfer_mfma<R><<<2 * BB * 16 * R, 256, 0, stream>>>(Aq, Bq, partial);
  chamfer_combine<R><<<TQ / 256, 256, 0, stream>>>(partial, yy, bsums);
  chamfer_final<<<1, 256, 0, stream>>>(bsums, out, TQ / 256);
}